// Round 2
// baseline (3771.384 us; speedup 1.0000x reference)
//
#include <hip/hip_runtime.h>
#include <math.h>

// ---------------- graph preprocessing ----------------

__global__ void deg_kernel(const int* __restrict__ src, const float* __restrict__ w,
                           float* __restrict__ deg, int ne) {
  int e = blockIdx.x * blockDim.x + threadIdx.x;
  if (e < ne) atomicAdd(&deg[src[e]], w[e]);
}

__global__ void dis_kernel(float* deg, int n) {
  int i = blockIdx.x * blockDim.x + threadIdx.x;
  if (i < n) {
    float d = deg[i];
    deg[i] = d > 0.f ? rsqrtf(fmaxf(d, 1e-30f)) : 0.f;
  }
}

__global__ void count_kernel(const int* __restrict__ dst, int* __restrict__ cnt, int ne) {
  int e = blockIdx.x * blockDim.x + threadIdx.x;
  if (e < ne) atomicAdd(&cnt[dst[e]], 1);
}

// single-block exclusive scan over n counts -> rowptr[0..n], cursor[i]=rowptr[i]
// cnt and cursor may alias.
__global__ __launch_bounds__(1024) void scan_kernel(const int* cnt, int* rowptr,
                                                    int* cursor, int n) {
  __shared__ int sums[1024];
  int tid = threadIdx.x;
  int chunk = (n + 1023) / 1024;
  int start = tid * chunk;
  int end = start + chunk; if (end > n) end = n;
  int s = 0;
  for (int i = start; i < end; ++i) s += cnt[i];
  sums[tid] = s;
  __syncthreads();
  for (int off = 1; off < 1024; off <<= 1) {
    int v = (tid >= off) ? sums[tid - off] : 0;
    __syncthreads();
    sums[tid] += v;
    __syncthreads();
  }
  int prefix = (tid > 0) ? sums[tid - 1] : 0;  // exclusive
  for (int i = start; i < end; ++i) {
    int cv = cnt[i];          // read BEFORE writing cursor (may alias)
    rowptr[i] = prefix;
    cursor[i] = prefix;
    prefix += cv;
  }
  if (tid == 0) rowptr[n] = sums[1023];
}

__global__ void scatter_kernel(const int* __restrict__ src, const int* __restrict__ dst,
                               const float* __restrict__ w, const float* __restrict__ dis,
                               int* __restrict__ cursor, int* __restrict__ col,
                               float* __restrict__ val, int ne) {
  int e = blockIdx.x * blockDim.x + threadIdx.x;
  if (e < ne) {
    int d = dst[e], s = src[e];
    int pos = atomicAdd(&cursor[d], 1);
    col[pos] = s;
    val[pos] = -(dis[s] * w[e] * dis[d]);
  }
}

// ---------------- SpMM: out[row] = alpha * sum_e val[e]*X[col[e]] - sub[row] ----------------
// blockDim.x == F (128 or 256); one block per row. out may alias sub.

__global__ void spmm_kernel(const int* __restrict__ rowptr, const int* __restrict__ col,
                            const float* __restrict__ val, const float* __restrict__ X,
                            float* __restrict__ out, const float* __restrict__ sub,
                            float alpha) {
  int row = blockIdx.x;
  int f = threadIdx.x;
  int F = blockDim.x;
  int e0 = rowptr[row], e1 = rowptr[row + 1];
  float acc = 0.f;
  for (int e = e0; e < e1; ++e)
    acc = fmaf(val[e], X[(long long)col[e] * F + f], acc);
  float r = alpha * acc;
  if (sub) r -= sub[(long long)row * F + f];
  out[(long long)row * F + f] = r;
}

// ---------------- fp32 GEMM, N=256 fixed: C[M,256] (+)= A[M,K] @ B[K,256] ----------------

template <int BETA>
__global__ __launch_bounds__(256) void gemm_kernel(const float* __restrict__ A,
                                                   const float* __restrict__ B,
                                                   float* __restrict__ C, int M, int K) {
  __shared__ float As[32][64];  // [k][m]
  __shared__ float Bs[32][64];  // [k][n]
  int tid = threadIdx.x;
  int tx = tid & 15, ty = tid >> 4;
  int row0 = blockIdx.x * 64, col0 = blockIdx.y * 64;
  float acc[4][4] = {};
  for (int k0 = 0; k0 < K; k0 += 32) {
    int r = tid >> 3;
    int c = (tid & 7) << 2;
#pragma unroll
    for (int h = 0; h < 2; ++h) {
      int rr = r + h * 32;
      int grow = row0 + rr;
      float4 v = make_float4(0.f, 0.f, 0.f, 0.f);
      if (grow < M) v = *(const float4*)(A + (long long)grow * K + k0 + c);
      As[c + 0][rr] = v.x; As[c + 1][rr] = v.y; As[c + 2][rr] = v.z; As[c + 3][rr] = v.w;
    }
    int br = tid >> 4;
    int bc = (tid & 15) << 2;
#pragma unroll
    for (int h = 0; h < 2; ++h) {
      int rr = br + h * 16;
      *(float4*)&Bs[rr][bc] = *(const float4*)(B + (long long)(k0 + rr) * 256 + col0 + bc);
    }
    __syncthreads();
#pragma unroll
    for (int kk = 0; kk < 32; ++kk) {
      float4 a = *(const float4*)&As[kk][ty << 2];
      float4 b = *(const float4*)&Bs[kk][tx << 2];
      float av[4] = {a.x, a.y, a.z, a.w}, bv[4] = {b.x, b.y, b.z, b.w};
#pragma unroll
      for (int i = 0; i < 4; ++i)
#pragma unroll
        for (int j = 0; j < 4; ++j) acc[i][j] = fmaf(av[i], bv[j], acc[i][j]);
    }
    __syncthreads();
  }
#pragma unroll
  for (int i = 0; i < 4; ++i) {
    int row = row0 + (ty << 2) + i;
    if (row < M) {
      float4* cp = (float4*)(C + (long long)row * 256 + col0 + (tx << 2));
      float4 v;
      if (BETA) {
        v = *cp;
        v.x += acc[i][0]; v.y += acc[i][1]; v.z += acc[i][2]; v.w += acc[i][3];
      } else {
        v = make_float4(acc[i][0], acc[i][1], acc[i][2], acc[i][3]);
      }
      *cp = v;
    }
  }
}

// ---------------- epilogue helpers ----------------

template <int RELU>
__global__ void bias_act_kernel(float* __restrict__ h, const float* __restrict__ b, int total) {
  int i = blockIdx.x * blockDim.x + threadIdx.x;
  if (i < total) {
    float v = h[i] + b[i & 255];
    h[i] = RELU ? fmaxf(v, 0.f) : v;
  }
}

__global__ void pool_kernel(const float* __restrict__ h, const int* __restrict__ batch,
                            float* __restrict__ sums, float* __restrict__ cnt) {
  int i = blockIdx.x;
  int f = threadIdx.x;  // 256
  int b = batch[i];
  atomicAdd(&sums[b * 256 + f], h[(long long)i * 256 + f]);
  if (f == 0) atomicAdd(&cnt[b], 1.f);
}

__global__ void head_kernel(const float* __restrict__ sums, const float* __restrict__ cnt,
                            const float* __restrict__ lw1, const float* __restrict__ lb1,
                            const float* __restrict__ lw2, const float* __restrict__ lb2,
                            float* __restrict__ out) {
  int g = blockIdx.x;
  int j = threadIdx.x;  // 256
  __shared__ float gs[256];
  __shared__ float red[256];
  float c = fmaxf(cnt[g], 1.f);
  gs[j] = fmaxf(sums[g * 256 + j] / c, 0.f);
  __syncthreads();
  float t = lb1[j];
  for (int i = 0; i < 256; ++i) t = fmaf(gs[i], lw1[i * 256 + j], t);
  red[j] = t * lw2[j];
  __syncthreads();
  for (int off = 128; off > 0; off >>= 1) {
    if (j < off) red[j] += red[j + off];
    __syncthreads();
  }
  if (j == 0) out[g] = 1.f / (1.f + expf(-(red[0] + lb2[0])));
}

// ---------------- host ----------------

extern "C" void kernel_launch(void* const* d_in, const int* in_sizes, int n_in,
                              void* d_out, int out_size, void* d_ws, size_t ws_size,
                              hipStream_t stream) {
  const float* x    = (const float*)d_in[0];
  const int*  ei    = (const int*)d_in[1];
  const float* ew   = (const float*)d_in[2];
  const int*  batch = (const int*)d_in[3];
  const float* W1 = (const float*)d_in[4];
  const float* b1 = (const float*)d_in[5];
  const float* W2 = (const float*)d_in[6];
  const float* b2 = (const float*)d_in[7];
  const float* W3 = (const float*)d_in[8];
  const float* b3 = (const float*)d_in[9];
  const float* lw1 = (const float*)d_in[10];
  const float* lb1 = (const float*)d_in[11];
  const float* lw2 = (const float*)d_in[12];
  const float* lb2 = (const float*)d_in[13];
  float* out = (float*)d_out;

  const int NE  = in_sizes[2];
  const int NB  = in_sizes[3];
  const int FIN = in_sizes[0] / NB;  // 128
  const int* src = ei;
  const int* dst = ei + NE;

  char* p = (char*)d_ws;
  auto alloc = [&](size_t bytes) {
    char* q = p;
    p += (bytes + 255) & ~(size_t)255;
    return q;
  };
  float* dis    = (float*)alloc((size_t)NB * 4);
  int*   rowptr = (int*)alloc((size_t)(NB + 1) * 4);
  int*   cursor = (int*)alloc((size_t)NB * 4);
  int*   col    = (int*)alloc((size_t)NE * 4);
  float* val    = (float*)alloc((size_t)NE * 4);
  float* BUF0   = (float*)alloc((size_t)NB * 256 * 4);
  float* BUF1   = (float*)alloc((size_t)NB * 256 * 4);
  float* BUF2   = (float*)alloc((size_t)NB * 256 * 4);
  float* BUF3   = (float*)alloc((size_t)NB * 256 * 4);
  float* psums  = (float*)alloc(64 * 256 * 4);
  float* pcnt   = (float*)alloc(64 * 4);

  hipMemsetAsync(dis, 0, (size_t)NB * 4, stream);
  hipMemsetAsync(cursor, 0, (size_t)NB * 4, stream);
  hipMemsetAsync(psums, 0, 64 * 256 * 4, stream);
  hipMemsetAsync(pcnt, 0, 64 * 4, stream);

  int eb = (NE + 255) / 256;
  deg_kernel<<<eb, 256, 0, stream>>>(src, ew, dis, NE);
  dis_kernel<<<(NB + 255) / 256, 256, 0, stream>>>(dis, NB);
  count_kernel<<<eb, 256, 0, stream>>>(dst, cursor, NE);
  scan_kernel<<<1, 1024, 0, stream>>>(cursor, rowptr, cursor, NB);
  scatter_kernel<<<eb, 256, 0, stream>>>(src, dst, ew, dis, cursor, col, val, NE);

  auto cheb = [&](const float* H, int Fin, const float* W, const float* b, bool relu,
                  float* B1, float* B2, float* OUT) {
    dim3 ggrid((NB + 63) / 64, 4);
    size_t wsz = (size_t)Fin * 256;
    // out = Tx0 @ W0
    gemm_kernel<0><<<ggrid, 256, 0, stream>>>(H, W, OUT, NB, Fin);
    // Tx1 = P(H)
    spmm_kernel<<<NB, Fin, 0, stream>>>(rowptr, col, val, H, B1, nullptr, 1.f);
    gemm_kernel<1><<<ggrid, 256, 0, stream>>>(B1, W + wsz, OUT, NB, Fin);
    // Tx2 = 2 P(Tx1) - Tx0
    spmm_kernel<<<NB, Fin, 0, stream>>>(rowptr, col, val, B1, B2, H, 2.f);
    gemm_kernel<1><<<ggrid, 256, 0, stream>>>(B2, W + 2 * wsz, OUT, NB, Fin);
    // Tx3 = 2 P(Tx2) - Tx1   (in-place over B1)
    spmm_kernel<<<NB, Fin, 0, stream>>>(rowptr, col, val, B2, B1, B1, 2.f);
    gemm_kernel<1><<<ggrid, 256, 0, stream>>>(B1, W + 3 * wsz, OUT, NB, Fin);
    // Tx4 = 2 P(Tx3) - Tx2   (in-place over B2)
    spmm_kernel<<<NB, Fin, 0, stream>>>(rowptr, col, val, B1, B2, B2, 2.f);
    gemm_kernel<1><<<ggrid, 256, 0, stream>>>(B2, W + 4 * wsz, OUT, NB, Fin);
    int total = NB * 256;
    if (relu)
      bias_act_kernel<1><<<(total + 255) / 256, 256, 0, stream>>>(OUT, b, total);
    else
      bias_act_kernel<0><<<(total + 255) / 256, 256, 0, stream>>>(OUT, b, total);
  };

  // layer 1: input x (F=128) -> BUF2 (relu)
  cheb(x, FIN, W1, b1, true, BUF0, BUF1, BUF2);
  // layer 2: BUF2 -> BUF3 (no relu)
  cheb(BUF2, 256, W2, b2, false, BUF0, BUF1, BUF3);
  // layer 3: BUF3 -> BUF2 (relu)
  cheb(BUF3, 256, W3, b3, true, BUF0, BUF1, BUF2);

  pool_kernel<<<NB, 256, 0, stream>>>(BUF2, batch, psums, pcnt);
  head_kernel<<<64, 256, 0, stream>>>(psums, pcnt, lw1, lb1, lw2, lb2, out);
}

// Round 4
// 1465.864 us; speedup vs baseline: 2.5728x; 2.5728x over previous
//
#include <hip/hip_runtime.h>
#include <math.h>

typedef unsigned int uint;
typedef unsigned short ushort;
typedef __bf16 bf16x8 __attribute__((ext_vector_type(8)));
typedef float f32x4 __attribute__((ext_vector_type(4)));
typedef __attribute__((address_space(1))) const void gvoid;
typedef __attribute__((address_space(3))) void svoid;

__device__ __forceinline__ float b2f(ushort u) {
  uint v = ((uint)u) << 16;
  return __uint_as_float(v);
}
__device__ __forceinline__ ushort f2b(float f) {
  uint u = __float_as_uint(f);
  u += 0x7FFFu + ((u >> 16) & 1u);  // RNE
  return (ushort)(u >> 16);
}
__device__ __forceinline__ uint pack2(float a, float b) {
  return (uint)f2b(a) | ((uint)f2b(b) << 16);
}

// ---------------- graph preprocessing ----------------

__global__ void deg_kernel(const int* __restrict__ src, const float* __restrict__ w,
                           float* __restrict__ deg, int ne) {
  int e = blockIdx.x * blockDim.x + threadIdx.x;
  if (e < ne) atomicAdd(&deg[src[e]], w[e]);
}

__global__ void dis_kernel(float* deg, int n) {
  int i = blockIdx.x * blockDim.x + threadIdx.x;
  if (i < n) {
    float d = deg[i];
    deg[i] = d > 0.f ? rsqrtf(fmaxf(d, 1e-30f)) : 0.f;
  }
}

__global__ void count_kernel(const int* __restrict__ dst, int* __restrict__ cnt, int ne) {
  int e = blockIdx.x * blockDim.x + threadIdx.x;
  if (e < ne) atomicAdd(&cnt[dst[e]], 1);
}

__global__ __launch_bounds__(1024) void scan_kernel(const int* cnt, int* rowptr,
                                                    int* cursor, int n) {
  __shared__ int sums[1024];
  int tid = threadIdx.x;
  int chunk = (n + 1023) / 1024;
  int start = tid * chunk;
  int end = start + chunk; if (end > n) end = n;
  int s = 0;
  for (int i = start; i < end; ++i) s += cnt[i];
  sums[tid] = s;
  __syncthreads();
  for (int off = 1; off < 1024; off <<= 1) {
    int v = (tid >= off) ? sums[tid - off] : 0;
    __syncthreads();
    sums[tid] += v;
    __syncthreads();
  }
  int prefix = (tid > 0) ? sums[tid - 1] : 0;
  for (int i = start; i < end; ++i) {
    int cv = cnt[i];  // read before cursor write (may alias)
    rowptr[i] = prefix;
    cursor[i] = prefix;
    prefix += cv;
  }
  if (tid == 0) rowptr[n] = sums[1023];
}

__global__ void scatter_kernel(const int* __restrict__ src, const int* __restrict__ dst,
                               const float* __restrict__ w, const float* __restrict__ dis,
                               int* __restrict__ cursor, int* __restrict__ col,
                               float* __restrict__ val, int ne) {
  int e = blockIdx.x * blockDim.x + threadIdx.x;
  if (e < ne) {
    int d = dst[e], s = src[e];
    int pos = atomicAdd(&cursor[d], 1);
    col[pos] = s;
    val[pos] = -(dis[s] * w[e] * dis[d]);
  }
}

// ---------------- conversions ----------------

// x fp32 [NB][FIN] -> bf16 pairs (uint) [NB][FIN/2]
__global__ void xcvt_kernel(const float* __restrict__ x, uint* __restrict__ o, int total) {
  int i = blockIdx.x * blockDim.x + threadIdx.x;
  if (i < total) {
    float2 v = *(const float2*)(x + (size_t)i * 2);
    o[i] = pack2(v.x, v.y);
  }
}

// W fp32 [5][Fin][256] -> WT bf16 [256][Ktot], Ktot=5*Fin, k = ord*Fin+fin
__global__ void wprep_kernel(const float* __restrict__ W, ushort* __restrict__ WT,
                             int shift, int Ktot, int total) {
  int id = blockIdx.x * blockDim.x + threadIdx.x;
  if (id >= total) return;
  int n = id / Ktot;
  int k = id - n * Ktot;
  int fin = k & ((1 << shift) - 1);
  int ord = k >> shift;
  WT[id] = f2b(W[(size_t)(ord << shift) * 256 + (size_t)fin * 256 + n]);
}

// ---------------- SpMM (bf16): out[row] = alpha * sum val*X[col] - sub[row] ----------------
// FHALF = F/2 threads per block (uint = 2 bf16 features), one block per row.

template <int FHALF>
__global__ void spmm_bf16(const int* __restrict__ rowptr, const int* __restrict__ col,
                          const float* __restrict__ val, const uint* __restrict__ X,
                          uint* __restrict__ out, const uint* __restrict__ sub,
                          float alpha) {
  int row = blockIdx.x;
  int t = threadIdx.x;
  int e0 = rowptr[row], e1 = rowptr[row + 1];
  float a0 = 0.f, a1 = 0.f;
  for (int e = e0; e < e1; ++e) {
    int c = col[e];
    float v = val[e];
    uint p = X[(size_t)c * FHALF + t];
    a0 = fmaf(v, b2f((ushort)(p & 0xFFFF)), a0);
    a1 = fmaf(v, b2f((ushort)(p >> 16)), a1);
  }
  float r0 = alpha * a0, r1 = alpha * a1;
  if (sub) {
    uint s = sub[(size_t)row * FHALF + t];
    r0 -= b2f((ushort)(s & 0xFFFF));
    r1 -= b2f((ushort)(s >> 16));
  }
  out[(size_t)row * FHALF + t] = pack2(r0, r1);
}

// ---------------- MFMA GEMM: C[M][256] = act(sum_ord Tx_ord @ W_ord + b) -> bf16 ----------------
// A: 5 bf16 buffers [M][Fin]; WT: bf16 [256][Ktot] (K-contiguous); tile 128x128, BK=64.
// LDS linear dest for global_load_lds; XOR swizzle ((row&7)<<4) applied on the
// global SOURCE address (inverse) and on ds_read (both-sides, rule #21).

struct APtrs { const ushort* p[5]; };

template <int RELU, int SHIFT>
__global__ __launch_bounds__(256, 2) void gemm_mfma(APtrs ap, const ushort* __restrict__ WT,
                                                    const float* __restrict__ bias,
                                                    ushort* __restrict__ C, int M, int Ktot) {
  constexpr int LDA = 1 << SHIFT;
  __shared__ __align__(16) char lAb[16384];  // [128 m][64 k] bf16, swizzled
  __shared__ __align__(16) char lBb[16384];  // [128 n][64 k] bf16, swizzled
  int tid = threadIdx.x;
  int lane = tid & 63, w = tid >> 6;
  int wr = w >> 1, wc = w & 1;
  int row0 = blockIdx.x * 128, col0 = blockIdx.y * 128;

  f32x4 acc[4][4];
#pragma unroll
  for (int i = 0; i < 4; ++i)
#pragma unroll
    for (int n = 0; n < 4; ++n) acc[i][n] = {0.f, 0.f, 0.f, 0.f};

  for (int k0 = 0; k0 < Ktot; k0 += 64) {
    const ushort* Ab = ap.p[k0 >> SHIFT];
    int ka = k0 & (LDA - 1);
    __syncthreads();  // previous iter's reads done before overwrite
    // stage A: 16 KB = 4 chunks x (256 threads x 16 B)
#pragma unroll
    for (int c = 0; c < 4; ++c) {
      int base = c * 4096 + w * 1024;
      int off = base + lane * 16;             // phys LDS byte this lane fills
      int row = off >> 7, within = off & 127;
      int lw = within ^ ((row & 7) << 4);     // inverse swizzle -> logical k-byte
      int grow = row0 + row; if (grow >= M) grow = M - 1;
      const ushort* g = Ab + (size_t)grow * LDA + ka + (lw >> 1);
      __builtin_amdgcn_global_load_lds((gvoid*)g, (svoid*)(lAb + base), 16, 0, 0);
    }
    // stage B: 16 KB = 4 chunks
#pragma unroll
    for (int c = 0; c < 4; ++c) {
      int base = c * 4096 + w * 1024;
      int off = base + lane * 16;
      int n = off >> 7, within = off & 127;
      int lw = within ^ ((n & 7) << 4);
      const ushort* g = WT + (size_t)(col0 + n) * Ktot + k0 + (lw >> 1);
      __builtin_amdgcn_global_load_lds((gvoid*)g, (svoid*)(lBb + base), 16, 0, 0);
    }
    asm volatile("s_waitcnt vmcnt(0)" ::: "memory");
    __syncthreads();
#pragma unroll
    for (int s = 0; s < 2; ++s) {
      int kb = (s << 6) + ((lane >> 4) << 4);  // k-byte base for this lane
      bf16x8 af[4], bfr[4];
#pragma unroll
      for (int i = 0; i < 4; ++i) {
        int mrow = (wr << 6) + (i << 4) + (lane & 15);
        af[i] = *(const bf16x8*)(lAb + (mrow << 7) + (kb ^ ((mrow & 7) << 4)));
      }
#pragma unroll
      for (int n = 0; n < 4; ++n) {
        int ncol = (wc << 6) + (n << 4) + (lane & 15);
        bfr[n] = *(const bf16x8*)(lBb + (ncol << 7) + (kb ^ ((ncol & 7) << 4)));
      }
#pragma unroll
      for (int i = 0; i < 4; ++i)
#pragma unroll
        for (int n = 0; n < 4; ++n)
          acc[i][n] = __builtin_amdgcn_mfma_f32_16x16x32_bf16(af[i], bfr[n], acc[i][n], 0, 0, 0);
    }
  }
  // epilogue: bias + act + bf16 store. D: col=lane&15, row=(lane>>4)*4+r
  int cb = col0 + (wc << 6) + (lane & 15);
  float bv[4];
#pragma unroll
  for (int n = 0; n < 4; ++n) bv[n] = bias[cb + (n << 4)];
#pragma unroll
  for (int i = 0; i < 4; ++i) {
    int rbase = row0 + (wr << 6) + (i << 4) + ((lane >> 4) << 2);
#pragma unroll
    for (int r = 0; r < 4; ++r) {
      int row = rbase + r;
      if (row < M) {
#pragma unroll
        for (int n = 0; n < 4; ++n) {
          float v = acc[i][n][r] + bv[n];
          if (RELU) v = fmaxf(v, 0.f);
          C[(size_t)row * 256 + cb + (n << 4)] = f2b(v);
        }
      }
    }
  }
}

// ---------------- pooling & head ----------------

__global__ void bounds_kernel(const int* __restrict__ batch, int nb, int ng,
                              int* __restrict__ bnd) {
  int g = threadIdx.x;
  if (g > ng) return;
  int lo = 0, hi = nb;
  while (lo < hi) {
    int mid = (lo + hi) >> 1;
    if (batch[mid] < g) lo = mid + 1; else hi = mid;
  }
  bnd[g] = lo;
}

// grid (NG, 8), block 128; h bf16 pairs [NB][128]
__global__ void pool_kernel(const uint* __restrict__ h, const int* __restrict__ bnd,
                            float* __restrict__ psums) {
  int g = blockIdx.x, chunk = blockIdx.y;
  int t = threadIdx.x;
  int s = bnd[g], e = bnd[g + 1];
  int n = e - s;
  int per = (n + (int)gridDim.y - 1) / (int)gridDim.y;
  int i0 = s + chunk * per;
  int i1 = i0 + per; if (i1 > e) i1 = e;
  float a0 = 0.f, a1 = 0.f;
  for (int i = i0; i < i1; ++i) {
    uint p = h[(size_t)i * 128 + t];
    a0 += b2f((ushort)(p & 0xFFFF));
    a1 += b2f((ushort)(p >> 16));
  }
  if (i0 < i1) {
    atomicAdd(&psums[g * 256 + 2 * t], a0);
    atomicAdd(&psums[g * 256 + 2 * t + 1], a1);
  }
}

__global__ void head_kernel(const float* __restrict__ psums, const int* __restrict__ bnd,
                            const float* __restrict__ lw1, const float* __restrict__ lb1,
                            const float* __restrict__ lw2, const float* __restrict__ lb2,
                            float* __restrict__ out) {
  int g = blockIdx.x;
  int j = threadIdx.x;  // 256
  __shared__ float gs[256];
  __shared__ float red[256];
  float c = fmaxf((float)(bnd[g + 1] - bnd[g]), 1.f);
  gs[j] = fmaxf(psums[g * 256 + j] / c, 0.f);
  __syncthreads();
  float t = lb1[j];
  for (int i = 0; i < 256; ++i) t = fmaf(gs[i], lw1[i * 256 + j], t);
  red[j] = t * lw2[j];
  __syncthreads();
  for (int off = 128; off > 0; off >>= 1) {
    if (j < off) red[j] += red[j + off];
    __syncthreads();
  }
  if (j == 0) out[g] = 1.f / (1.f + expf(-(red[0] + lb2[0])));
}

// ---------------- host ----------------

extern "C" void kernel_launch(void* const* d_in, const int* in_sizes, int n_in,
                              void* d_out, int out_size, void* d_ws, size_t ws_size,
                              hipStream_t stream) {
  const float* x    = (const float*)d_in[0];
  const int*   ei   = (const int*)d_in[1];
  const float* ew   = (const float*)d_in[2];
  const int*   batch= (const int*)d_in[3];
  const float* W1 = (const float*)d_in[4];
  const float* b1 = (const float*)d_in[5];
  const float* W2 = (const float*)d_in[6];
  const float* b2 = (const float*)d_in[7];
  const float* W3 = (const float*)d_in[8];
  const float* b3 = (const float*)d_in[9];
  const float* lw1 = (const float*)d_in[10];
  const float* lb1 = (const float*)d_in[11];
  const float* lw2 = (const float*)d_in[12];
  const float* lb2 = (const float*)d_in[13];
  float* out = (float*)d_out;

  const int NE  = in_sizes[2];
  const int NB  = in_sizes[3];
  const int FIN = in_sizes[0] / NB;  // 128
  const int NG  = out_size;          // 64
  const int* src = ei;
  const int* dst = ei + NE;

  char* p = (char*)d_ws;
  auto alloc = [&](size_t bytes) {
    char* q = p;
    p += (bytes + 255) & ~(size_t)255;
    return q;
  };
  float* dis    = (float*)alloc((size_t)NB * 4);
  int*   rowptr = (int*)alloc((size_t)(NB + 1) * 4);
  int*   cursor = (int*)alloc((size_t)NB * 4);
  int*   col    = (int*)alloc((size_t)NE * 4);
  float* val    = (float*)alloc((size_t)NE * 4);
  int*   bnd    = (int*)alloc((size_t)(NG + 1) * 4);
  uint*  X0     = (uint*)alloc((size_t)NB * (FIN / 2) * 4);   // x in bf16 pairs
  uint*  T1     = (uint*)alloc((size_t)NB * 128 * 4);
  uint*  T2     = (uint*)alloc((size_t)NB * 128 * 4);
  uint*  T3     = (uint*)alloc((size_t)NB * 128 * 4);
  uint*  T4     = (uint*)alloc((size_t)NB * 128 * 4);
  uint*  HA     = (uint*)alloc((size_t)NB * 128 * 4);         // layer outputs (bf16 pairs)
  uint*  HB     = (uint*)alloc((size_t)NB * 128 * 4);
  ushort* WT1   = (ushort*)alloc((size_t)256 * 5 * FIN * 2);
  ushort* WT2   = (ushort*)alloc((size_t)256 * 5 * 256 * 2);
  ushort* WT3   = (ushort*)alloc((size_t)256 * 5 * 256 * 2);
  float* psums  = (float*)alloc((size_t)NG * 256 * 4);

  hipMemsetAsync(dis, 0, (size_t)NB * 4, stream);
  hipMemsetAsync(cursor, 0, (size_t)NB * 4, stream);
  hipMemsetAsync(psums, 0, (size_t)NG * 256 * 4, stream);

  int eb = (NE + 255) / 256;
  deg_kernel<<<eb, 256, 0, stream>>>(src, ew, dis, NE);
  dis_kernel<<<(NB + 255) / 256, 256, 0, stream>>>(dis, NB);
  count_kernel<<<eb, 256, 0, stream>>>(dst, cursor, NE);
  scan_kernel<<<1, 1024, 0, stream>>>(cursor, rowptr, cursor, NB);
  scatter_kernel<<<eb, 256, 0, stream>>>(src, dst, ew, dis, cursor, col, val, NE);

  int xcnt = NB * (FIN / 2);
  xcvt_kernel<<<(xcnt + 255) / 256, 256, 0, stream>>>(x, X0, xcnt);
  {
    int kt1 = 5 * FIN, tot1 = 256 * kt1;
    wprep_kernel<<<(tot1 + 255) / 256, 256, 0, stream>>>(W1, WT1, 7, kt1, tot1);
    int kt2 = 5 * 256, tot2 = 256 * kt2;
    wprep_kernel<<<(tot2 + 255) / 256, 256, 0, stream>>>(W2, WT2, 8, kt2, tot2);
    wprep_kernel<<<(tot2 + 255) / 256, 256, 0, stream>>>(W3, WT3, 8, kt2, tot2);
  }
  bounds_kernel<<<1, 128, 0, stream>>>(batch, NB, NG, bnd);

  dim3 ggrid((NB + 127) / 128, 2);

  // ---- layer 1 (Fin=128, relu) ----
  spmm_bf16<64><<<NB, 64, 0, stream>>>(rowptr, col, val, X0, T1, nullptr, 1.f);
  spmm_bf16<64><<<NB, 64, 0, stream>>>(rowptr, col, val, T1, T2, X0, 2.f);
  spmm_bf16<64><<<NB, 64, 0, stream>>>(rowptr, col, val, T2, T3, T1, 2.f);
  spmm_bf16<64><<<NB, 64, 0, stream>>>(rowptr, col, val, T3, T4, T2, 2.f);
  {
    APtrs ap = {{(const ushort*)X0, (const ushort*)T1, (const ushort*)T2,
                 (const ushort*)T3, (const ushort*)T4}};
    gemm_mfma<1, 7><<<ggrid, 256, 0, stream>>>(ap, WT1, b1, (ushort*)HA, NB, 5 * FIN);
  }
  // ---- layer 2 (Fin=256, no relu) ----
  spmm_bf16<128><<<NB, 128, 0, stream>>>(rowptr, col, val, HA, T1, nullptr, 1.f);
  spmm_bf16<128><<<NB, 128, 0, stream>>>(rowptr, col, val, T1, T2, HA, 2.f);
  spmm_bf16<128><<<NB, 128, 0, stream>>>(rowptr, col, val, T2, T3, T1, 2.f);
  spmm_bf16<128><<<NB, 128, 0, stream>>>(rowptr, col, val, T3, T4, T2, 2.f);
  {
    APtrs ap = {{(const ushort*)HA, (const ushort*)T1, (const ushort*)T2,
                 (const ushort*)T3, (const ushort*)T4}};
    gemm_mfma<0, 8><<<ggrid, 256, 0, stream>>>(ap, WT2, b2, (ushort*)HB, NB, 5 * 256);
  }
  // ---- layer 3 (Fin=256, relu) ----
  spmm_bf16<128><<<NB, 128, 0, stream>>>(rowptr, col, val, HB, T1, nullptr, 1.f);
  spmm_bf16<128><<<NB, 128, 0, stream>>>(rowptr, col, val, T1, T2, HB, 2.f);
  spmm_bf16<128><<<NB, 128, 0, stream>>>(rowptr, col, val, T2, T3, T1, 2.f);
  spmm_bf16<128><<<NB, 128, 0, stream>>>(rowptr, col, val, T3, T4, T2, 2.f);
  {
    APtrs ap = {{(const ushort*)HB, (const ushort*)T1, (const ushort*)T2,
                 (const ushort*)T3, (const ushort*)T4}};
    gemm_mfma<1, 8><<<ggrid, 256, 0, stream>>>(ap, WT3, b3, (ushort*)HA, NB, 5 * 256);
  }

  pool_kernel<<<dim3(NG, 8), 128, 0, stream>>>(HA, bnd, psums);
  head_kernel<<<NG, 256, 0, stream>>>(psums, bnd, lw1, lb1, lw2, lb2, out);
}

// Round 6
// 1053.537 us; speedup vs baseline: 3.5797x; 1.3914x over previous
//
#include <hip/hip_runtime.h>
#include <math.h>

typedef unsigned int uint;
typedef unsigned short ushort;
typedef __bf16 bf16x8 __attribute__((ext_vector_type(8)));
typedef float f32x4 __attribute__((ext_vector_type(4)));
typedef __attribute__((address_space(1))) const void gvoid;
typedef __attribute__((address_space(3))) void svoid;

__device__ __forceinline__ float b2f(ushort u) {
  uint v = ((uint)u) << 16;
  return __uint_as_float(v);
}
__device__ __forceinline__ ushort f2b(float f) {
  uint u = __float_as_uint(f);
  u += 0x7FFFu + ((u >> 16) & 1u);  // RNE
  return (ushort)(u >> 16);
}
__device__ __forceinline__ uint pack2(float a, float b) {
  return (uint)f2b(a) | ((uint)f2b(b) << 16);
}

// ---------------- preprocessing ----------------

// one edge pass: deg[src]+=w, cnt[dst]+=1
__global__ void edge_kernel(const int* __restrict__ src, const int* __restrict__ dst,
                            const float* __restrict__ w, float* __restrict__ deg,
                            int* __restrict__ cnt, int ne) {
  int e = blockIdx.x * blockDim.x + threadIdx.x;
  if (e < ne) {
    atomicAdd(&deg[src[e]], w[e]);
    atomicAdd(&cnt[dst[e]], 1);
  }
}

// one node pass: dis (in-place over deg), CSR range alloc (block scan + 1 atomic),
// cursor init; block 0 also computes graph bounds via binary search on sorted batch.
__global__ __launch_bounds__(256) void node_kernel(float* __restrict__ deg,
                                                   const int* __restrict__ cnt,
                                                   int* __restrict__ rowstart,
                                                   int* __restrict__ cursor,
                                                   int* __restrict__ total,
                                                   const int* __restrict__ batch,
                                                   int nb, int ng, int* __restrict__ bnd) {
  __shared__ int ls[256];
  __shared__ int base;
  int tid = threadIdx.x;
  int i = blockIdx.x * 256 + tid;
  int c = (i < nb) ? cnt[i] : 0;
  ls[tid] = c;
  __syncthreads();
  for (int off = 1; off < 256; off <<= 1) {
    int v = (tid >= off) ? ls[tid - off] : 0;
    __syncthreads();
    ls[tid] += v;
    __syncthreads();
  }
  if (tid == 255) base = atomicAdd(total, ls[255]);
  __syncthreads();
  if (i < nb) {
    int pos = base + ls[tid] - c;  // exclusive within block
    rowstart[i] = pos;
    cursor[i] = pos;
    float d = deg[i];
    deg[i] = d > 0.f ? rsqrtf(fmaxf(d, 1e-30f)) : 0.f;
  }
  if (blockIdx.x == 0 && tid <= ng) {
    int lo = 0, hi = nb;
    while (lo < hi) {
      int mid = (lo + hi) >> 1;
      if (batch[mid] < tid) lo = mid + 1; else hi = mid;
    }
    bnd[tid] = lo;
  }
}

// cv[pos] = (src, -dis[s]*w*dis[d]) interleaved for scalar-load in SpMM
__global__ void scatter_kernel(const int* __restrict__ src, const int* __restrict__ dst,
                               const float* __restrict__ w, const float* __restrict__ dis,
                               int* __restrict__ cursor, int2* __restrict__ cv, int ne) {
  int e = blockIdx.x * blockDim.x + threadIdx.x;
  if (e < ne) {
    int d = dst[e], s = src[e];
    int pos = atomicAdd(&cursor[d], 1);
    float v = -(dis[s] * w[e] * dis[d]);
    cv[pos] = make_int2(s, __float_as_int(v));
  }
}

// ---------------- conversions ----------------

// x fp32 [NB][FIN] -> bf16 pairs (uint) [NB][FIN/2]
__global__ void xcvt_kernel(const float* __restrict__ x, uint* __restrict__ o, int total) {
  int i = blockIdx.x * blockDim.x + threadIdx.x;
  if (i < total) {
    float2 v = *(const float2*)(x + (size_t)i * 2);
    o[i] = pack2(v.x, v.y);
  }
}

// W fp32 [5][Fin][256] -> WT bf16 [256][Ktot], Ktot=5*Fin, k = ord*Fin+fin
__global__ void wprep_kernel(const float* __restrict__ W, ushort* __restrict__ WT,
                             int shift, int Ktot, int total) {
  int id = blockIdx.x * blockDim.x + threadIdx.x;
  if (id >= total) return;
  int n = id / Ktot;
  int k = id - n * Ktot;
  int fin = k & ((1 << shift) - 1);
  int ord = k >> shift;
  WT[id] = f2b(W[(size_t)(ord << shift) * 256 + (size_t)fin * 256 + n]);
}

// both 256-in weight tensors in one launch
__global__ void wprep2_kernel(const float* __restrict__ W2, ushort* __restrict__ WT2,
                              const float* __restrict__ W3, ushort* __restrict__ WT3,
                              int tot) {
  int id = blockIdx.x * blockDim.x + threadIdx.x;
  if (id >= 2 * tot) return;
  const float* W = (id < tot) ? W2 : W3;
  ushort* WT = (id < tot) ? WT2 : WT3;
  int t = (id < tot) ? id : id - tot;
  int n = t / 1280;
  int k = t - n * 1280;
  int fin = k & 255;
  int ord = k >> 8;
  WT[t] = f2b(W[(size_t)(ord << 8) * 256 + (size_t)fin * 256 + n]);
}

// ---------------- SpMM: one wave per row ----------------
// WIDE=1: F=256 (uint2/lane), WIDE=0: F=128 (uint/lane). 4 rows per 256-thr block.
// out[row] = alpha * sum val*X[col] - sub[row]

template <int WIDE>
__global__ __launch_bounds__(256) void spmm_wave(const int* __restrict__ rowstart,
                                                 const int* __restrict__ rowcnt,
                                                 const int2* __restrict__ cv,
                                                 const uint* __restrict__ X,
                                                 uint* __restrict__ out,
                                                 const uint* __restrict__ sub,
                                                 float alpha, int nb) {
  int row = blockIdx.x * 4 + (threadIdx.x >> 6);
  if (row >= nb) return;
  int lane = threadIdx.x & 63;
  int e0 = __builtin_amdgcn_readfirstlane(rowstart[row]);
  int cnt = __builtin_amdgcn_readfirstlane(rowcnt[row]);
  int e1 = e0 + cnt;
  float a0 = 0.f, a1 = 0.f, a2 = 0.f, a3 = 0.f;
  int e = e0;
  if (WIDE) {
    const uint2* Xr = (const uint2*)X;
    for (; e + 2 <= e1; e += 2) {
      int2 p0 = cv[e], p1 = cv[e + 1];
      int c0 = __builtin_amdgcn_readfirstlane(p0.x);
      float v0 = __uint_as_float(__builtin_amdgcn_readfirstlane((uint)p0.y));
      int c1 = __builtin_amdgcn_readfirstlane(p1.x);
      float v1 = __uint_as_float(__builtin_amdgcn_readfirstlane((uint)p1.y));
      uint2 g0 = Xr[(size_t)c0 * 64 + lane];
      uint2 g1 = Xr[(size_t)c1 * 64 + lane];
      a0 = fmaf(v0, b2f((ushort)(g0.x & 0xFFFF)), a0);
      a1 = fmaf(v0, b2f((ushort)(g0.x >> 16)), a1);
      a2 = fmaf(v0, b2f((ushort)(g0.y & 0xFFFF)), a2);
      a3 = fmaf(v0, b2f((ushort)(g0.y >> 16)), a3);
      a0 = fmaf(v1, b2f((ushort)(g1.x & 0xFFFF)), a0);
      a1 = fmaf(v1, b2f((ushort)(g1.x >> 16)), a1);
      a2 = fmaf(v1, b2f((ushort)(g1.y & 0xFFFF)), a2);
      a3 = fmaf(v1, b2f((ushort)(g1.y >> 16)), a3);
    }
    if (e < e1) {
      int2 p0 = cv[e];
      int c0 = __builtin_amdgcn_readfirstlane(p0.x);
      float v0 = __uint_as_float(__builtin_amdgcn_readfirstlane((uint)p0.y));
      uint2 g0 = Xr[(size_t)c0 * 64 + lane];
      a0 = fmaf(v0, b2f((ushort)(g0.x & 0xFFFF)), a0);
      a1 = fmaf(v0, b2f((ushort)(g0.x >> 16)), a1);
      a2 = fmaf(v0, b2f((ushort)(g0.y & 0xFFFF)), a2);
      a3 = fmaf(v0, b2f((ushort)(g0.y >> 16)), a3);
    }
    float r0 = alpha * a0, r1 = alpha * a1, r2 = alpha * a2, r3 = alpha * a3;
    if (sub) {
      uint2 s = ((const uint2*)sub)[(size_t)row * 64 + lane];
      r0 -= b2f((ushort)(s.x & 0xFFFF));
      r1 -= b2f((ushort)(s.x >> 16));
      r2 -= b2f((ushort)(s.y & 0xFFFF));
      r3 -= b2f((ushort)(s.y >> 16));
    }
    ((uint2*)out)[(size_t)row * 64 + lane] = make_uint2(pack2(r0, r1), pack2(r2, r3));
  } else {
    for (; e + 2 <= e1; e += 2) {
      int2 p0 = cv[e], p1 = cv[e + 1];
      int c0 = __builtin_amdgcn_readfirstlane(p0.x);
      float v0 = __uint_as_float(__builtin_amdgcn_readfirstlane((uint)p0.y));
      int c1 = __builtin_amdgcn_readfirstlane(p1.x);
      float v1 = __uint_as_float(__builtin_amdgcn_readfirstlane((uint)p1.y));
      uint g0 = X[(size_t)c0 * 64 + lane];
      uint g1 = X[(size_t)c1 * 64 + lane];
      a0 = fmaf(v0, b2f((ushort)(g0 & 0xFFFF)), a0);
      a1 = fmaf(v0, b2f((ushort)(g0 >> 16)), a1);
      a0 = fmaf(v1, b2f((ushort)(g1 & 0xFFFF)), a0);
      a1 = fmaf(v1, b2f((ushort)(g1 >> 16)), a1);
    }
    if (e < e1) {
      int2 p0 = cv[e];
      int c0 = __builtin_amdgcn_readfirstlane(p0.x);
      float v0 = __uint_as_float(__builtin_amdgcn_readfirstlane((uint)p0.y));
      uint g0 = X[(size_t)c0 * 64 + lane];
      a0 = fmaf(v0, b2f((ushort)(g0 & 0xFFFF)), a0);
      a1 = fmaf(v0, b2f((ushort)(g0 >> 16)), a1);
    }
    float r0 = alpha * a0, r1 = alpha * a1;
    if (sub) {
      uint s = sub[(size_t)row * 64 + lane];
      r0 -= b2f((ushort)(s & 0xFFFF));
      r1 -= b2f((ushort)(s >> 16));
    }
    out[(size_t)row * 64 + lane] = pack2(r0, r1);
  }
}

// ---------------- MFMA GEMM: C[M][256] = act(sum_ord Tx_ord @ W_ord + b) -> bf16 ----------------
// A: 5 bf16 buffers [M][Fin]; WT: bf16 [256][Ktot] (K-contiguous); tile 128x128, BK=64.
// LDS linear dest for global_load_lds; XOR swizzle ((row&7)<<4) on the global
// SOURCE address (inverse) and on ds_read (both-sides, rule #21).

struct APtrs { const ushort* p[5]; };

template <int RELU, int SHIFT>
__global__ __launch_bounds__(256, 2) void gemm_mfma(APtrs ap, const ushort* __restrict__ WT,
                                                    const float* __restrict__ bias,
                                                    ushort* __restrict__ C, int M, int Ktot) {
  constexpr int LDA = 1 << SHIFT;
  __shared__ __align__(16) char lAb[16384];  // [128 m][64 k] bf16, swizzled
  __shared__ __align__(16) char lBb[16384];  // [128 n][64 k] bf16, swizzled
  int tid = threadIdx.x;
  int lane = tid & 63, w = tid >> 6;
  int wr = w >> 1, wc = w & 1;
  int row0 = blockIdx.x * 128, col0 = blockIdx.y * 128;

  f32x4 acc[4][4];
#pragma unroll
  for (int i = 0; i < 4; ++i)
#pragma unroll
    for (int n = 0; n < 4; ++n) acc[i][n] = {0.f, 0.f, 0.f, 0.f};

  for (int k0 = 0; k0 < Ktot; k0 += 64) {
    const ushort* Ab = ap.p[k0 >> SHIFT];
    int ka = k0 & (LDA - 1);
    __syncthreads();  // previous iter's reads done before overwrite
    // stage A: 16 KB = 4 chunks x (256 threads x 16 B)
#pragma unroll
    for (int c = 0; c < 4; ++c) {
      int base = c * 4096 + w * 1024;
      int off = base + lane * 16;             // phys LDS byte this lane fills
      int row = off >> 7, within = off & 127;
      int lw = within ^ ((row & 7) << 4);     // inverse swizzle -> logical k-byte
      int grow = row0 + row; if (grow >= M) grow = M - 1;
      const ushort* g = Ab + (size_t)grow * LDA + ka + (lw >> 1);
      __builtin_amdgcn_global_load_lds((gvoid*)g, (svoid*)(lAb + base), 16, 0, 0);
    }
    // stage B: 16 KB = 4 chunks
#pragma unroll
    for (int c = 0; c < 4; ++c) {
      int base = c * 4096 + w * 1024;
      int off = base + lane * 16;
      int n = off >> 7, within = off & 127;
      int lw = within ^ ((n & 7) << 4);
      const ushort* g = WT + (size_t)(col0 + n) * Ktot + k0 + (lw >> 1);
      __builtin_amdgcn_global_load_lds((gvoid*)g, (svoid*)(lBb + base), 16, 0, 0);
    }
    asm volatile("s_waitcnt vmcnt(0)" ::: "memory");
    __syncthreads();
#pragma unroll
    for (int s = 0; s < 2; ++s) {
      int kb = (s << 6) + ((lane >> 4) << 4);  // k-byte base for this lane
      bf16x8 af[4], bfr[4];
#pragma unroll
      for (int i = 0; i < 4; ++i) {
        int mrow = (wr << 6) + (i << 4) + (lane & 15);
        af[i] = *(const bf16x8*)(lAb + (mrow << 7) + (kb ^ ((mrow & 7) << 4)));
      }
#pragma unroll
      for (int n = 0; n < 4; ++n) {
        int ncol = (wc << 6) + (n << 4) + (lane & 15);
        bfr[n] = *(const bf16x8*)(lBb + (ncol << 7) + (kb ^ ((ncol & 7) << 4)));
      }
#pragma unroll
      for (int i = 0; i < 4; ++i)
#pragma unroll
        for (int n = 0; n < 4; ++n)
          acc[i][n] = __builtin_amdgcn_mfma_f32_16x16x32_bf16(af[i], bfr[n], acc[i][n], 0, 0, 0);
    }
  }
  // epilogue: bias + act + bf16 store. D: col=lane&15, row=(lane>>4)*4+r
  int cb = col0 + (wc << 6) + (lane & 15);
  float bv[4];
#pragma unroll
  for (int n = 0; n < 4; ++n) bv[n] = bias[cb + (n << 4)];
#pragma unroll
  for (int i = 0; i < 4; ++i) {
    int rbase = row0 + (wr << 6) + (i << 4) + ((lane >> 4) << 2);
#pragma unroll
    for (int r = 0; r < 4; ++r) {
      int row = rbase + r;
      if (row < M) {
#pragma unroll
        for (int n = 0; n < 4; ++n) {
          float v = acc[i][n][r] + bv[n];
          if (RELU) v = fmaxf(v, 0.f);
          C[(size_t)row * 256 + cb + (n << 4)] = f2b(v);
        }
      }
    }
  }
}

// ---------------- fused pool + head: one block per graph ----------------

__global__ __launch_bounds__(256) void head_kernel(const uint* __restrict__ h,
                                                   const int* __restrict__ bnd,
                                                   const float* __restrict__ lw1,
                                                   const float* __restrict__ lb1,
                                                   const float* __restrict__ lw2,
                                                   const float* __restrict__ lb2,
                                                   float* __restrict__ out) {
  int g = blockIdx.x;
  int j = threadIdx.x;  // 256 -> feature j
  __shared__ float gs[256];
  __shared__ float red[256];
  int s = bnd[g], e = bnd[g + 1];
  int ui = j >> 1, half = j & 1;
  float acc = 0.f;
  int i = s;
  for (; i + 4 <= e; i += 4) {
    uint p0 = h[(size_t)(i + 0) * 128 + ui];
    uint p1 = h[(size_t)(i + 1) * 128 + ui];
    uint p2 = h[(size_t)(i + 2) * 128 + ui];
    uint p3 = h[(size_t)(i + 3) * 128 + ui];
    acc += b2f((ushort)(half ? (p0 >> 16) : (p0 & 0xFFFF)));
    acc += b2f((ushort)(half ? (p1 >> 16) : (p1 & 0xFFFF)));
    acc += b2f((ushort)(half ? (p2 >> 16) : (p2 & 0xFFFF)));
    acc += b2f((ushort)(half ? (p3 >> 16) : (p3 & 0xFFFF)));
  }
  for (; i < e; ++i) {
    uint p = h[(size_t)i * 128 + ui];
    acc += b2f((ushort)(half ? (p >> 16) : (p & 0xFFFF)));
  }
  float c = fmaxf((float)(e - s), 1.f);
  gs[j] = fmaxf(acc / c, 0.f);
  __syncthreads();
  float t = lb1[j];
  for (int k = 0; k < 256; ++k) t = fmaf(gs[k], lw1[k * 256 + j], t);
  red[j] = t * lw2[j];
  __syncthreads();
  for (int off = 128; off > 0; off >>= 1) {
    if (j < off) red[j] += red[j + off];
    __syncthreads();
  }
  if (j == 0) out[g] = 1.f / (1.f + expf(-(red[0] + lb2[0])));
}

// ---------------- host ----------------

extern "C" void kernel_launch(void* const* d_in, const int* in_sizes, int n_in,
                              void* d_out, int out_size, void* d_ws, size_t ws_size,
                              hipStream_t stream) {
  const float* x    = (const float*)d_in[0];
  const int*   ei   = (const int*)d_in[1];
  const float* ew   = (const float*)d_in[2];
  const int*   batch= (const int*)d_in[3];
  const float* W1 = (const float*)d_in[4];
  const float* b1 = (const float*)d_in[5];
  const float* W2 = (const float*)d_in[6];
  const float* b2 = (const float*)d_in[7];
  const float* W3 = (const float*)d_in[8];
  const float* b3 = (const float*)d_in[9];
  const float* lw1 = (const float*)d_in[10];
  const float* lb1 = (const float*)d_in[11];
  const float* lw2 = (const float*)d_in[12];
  const float* lb2 = (const float*)d_in[13];
  float* out = (float*)d_out;

  const int NE  = in_sizes[2];
  const int NB  = in_sizes[3];
  const int FIN = in_sizes[0] / NB;  // 128
  const int NG  = out_size;          // 64
  const int* src = ei;
  const int* dst = ei + NE;

  char* p = (char*)d_ws;
  auto alloc = [&](size_t bytes) {
    char* q = p;
    p += (bytes + 255) & ~(size_t)255;
    return q;
  };
  // zero block: deg[NB] f32 | cnt[NB] i32 | total i32  (one memset)
  char* zb = (char*)alloc((size_t)(2 * NB + 1) * 4);
  float* deg  = (float*)zb;            // becomes dis in node_kernel
  int*   cnt  = (int*)(zb + (size_t)NB * 4);
  int*   total= (int*)(zb + (size_t)2 * NB * 4);
  int*   rowstart = (int*)alloc((size_t)NB * 4);
  int*   cursor   = (int*)alloc((size_t)NB * 4);
  int2*  cv       = (int2*)alloc((size_t)NE * 8);
  int*   bnd      = (int*)alloc((size_t)(NG + 1) * 4);
  uint*  X0  = (uint*)alloc((size_t)NB * (FIN / 2) * 4);
  uint*  T1  = (uint*)alloc((size_t)NB * 128 * 4);
  uint*  T2  = (uint*)alloc((size_t)NB * 128 * 4);
  uint*  T3  = (uint*)alloc((size_t)NB * 128 * 4);
  uint*  T4  = (uint*)alloc((size_t)NB * 128 * 4);
  uint*  HA  = (uint*)alloc((size_t)NB * 128 * 4);
  uint*  HB  = (uint*)alloc((size_t)NB * 128 * 4);
  ushort* WT1 = (ushort*)alloc((size_t)256 * 5 * FIN * 2);
  ushort* WT2 = (ushort*)alloc((size_t)256 * 5 * 256 * 2);
  ushort* WT3 = (ushort*)alloc((size_t)256 * 5 * 256 * 2);

  hipMemsetAsync(zb, 0, (size_t)(2 * NB + 1) * 4, stream);

  int eb = (NE + 255) / 256;
  int nbb = (NB + 255) / 256;
  edge_kernel<<<eb, 256, 0, stream>>>(src, dst, ew, deg, cnt, NE);
  node_kernel<<<nbb, 256, 0, stream>>>(deg, cnt, rowstart, cursor, total, batch, NB, NG, bnd);
  scatter_kernel<<<eb, 256, 0, stream>>>(src, dst, ew, deg, cursor, cv, NE);

  int xcnt = NB * (FIN / 2);
  xcvt_kernel<<<(xcnt + 255) / 256, 256, 0, stream>>>(x, X0, xcnt);
  {
    int kt1 = 5 * FIN, tot1 = 256 * kt1;
    wprep_kernel<<<(tot1 + 255) / 256, 256, 0, stream>>>(W1, WT1, 7, kt1, tot1);
    int tot2 = 256 * 1280;
    wprep2_kernel<<<(2 * tot2 + 255) / 256, 256, 0, stream>>>(W2, WT2, W3, WT3, tot2);
  }

  int sgrid = (NB + 3) / 4;
  dim3 ggrid((NB + 127) / 128, 2);

  // ---- layer 1 (Fin=128, relu) ----
  spmm_wave<0><<<sgrid, 256, 0, stream>>>(rowstart, cnt, cv, X0, T1, nullptr, 1.f, NB);
  spmm_wave<0><<<sgrid, 256, 0, stream>>>(rowstart, cnt, cv, T1, T2, X0, 2.f, NB);
  spmm_wave<0><<<sgrid, 256, 0, stream>>>(rowstart, cnt, cv, T2, T3, T1, 2.f, NB);
  spmm_wave<0><<<sgrid, 256, 0, stream>>>(rowstart, cnt, cv, T3, T4, T2, 2.f, NB);
  {
    APtrs ap = {{(const ushort*)X0, (const ushort*)T1, (const ushort*)T2,
                 (const ushort*)T3, (const ushort*)T4}};
    gemm_mfma<1, 7><<<ggrid, 256, 0, stream>>>(ap, WT1, b1, (ushort*)HA, NB, 5 * FIN);
  }
  // ---- layer 2 (Fin=256, no relu) ----
  spmm_wave<1><<<sgrid, 256, 0, stream>>>(rowstart, cnt, cv, HA, T1, nullptr, 1.f, NB);
  spmm_wave<1><<<sgrid, 256, 0, stream>>>(rowstart, cnt, cv, T1, T2, HA, 2.f, NB);
  spmm_wave<1><<<sgrid, 256, 0, stream>>>(rowstart, cnt, cv, T2, T3, T1, 2.f, NB);
  spmm_wave<1><<<sgrid, 256, 0, stream>>>(rowstart, cnt, cv, T3, T4, T2, 2.f, NB);
  {
    APtrs ap = {{(const ushort*)HA, (const ushort*)T1, (const ushort*)T2,
                 (const ushort*)T3, (const ushort*)T4}};
    gemm_mfma<0, 8><<<ggrid, 256, 0, stream>>>(ap, WT2, b2, (ushort*)HB, NB, 5 * 256);
  }
  // ---- layer 3 (Fin=256, relu) ----
  spmm_wave<1><<<sgrid, 256, 0, stream>>>(rowstart, cnt, cv, HB, T1, nullptr, 1.f, NB);
  spmm_wave<1><<<sgrid, 256, 0, stream>>>(rowstart, cnt, cv, T1, T2, HB, 2.f, NB);
  spmm_wave<1><<<sgrid, 256, 0, stream>>>(rowstart, cnt, cv, T2, T3, T1, 2.f, NB);
  spmm_wave<1><<<sgrid, 256, 0, stream>>>(rowstart, cnt, cv, T3, T4, T2, 2.f, NB);
  {
    APtrs ap = {{(const ushort*)HB, (const ushort*)T1, (const ushort*)T2,
                 (const ushort*)T3, (const ushort*)T4}};
    gemm_mfma<1, 8><<<ggrid, 256, 0, stream>>>(ap, WT3, b3, (ushort*)HA, NB, 5 * 256);
  }

  head_kernel<<<NG, 256, 0, stream>>>(HA, bnd, lw1, lb1, lw2, lb2, out);
}